// Round 2
// baseline (1230.495 us; speedup 1.0000x reference)
//
#include <hip/hip_runtime.h>
#include <stdint.h>
#include <stddef.h>

// ---------------------------------------------------------------------------
// GQA forward: y = Attn(RoPE(x@Wq), RoPE(x@Wk), x@Wv) @ Wo
// B=2 S=2048 D=4096 H=32 KVH=8 Dh=128, causal, fp32 in/out, bf16 MFMA compute.
// ---------------------------------------------------------------------------

typedef __bf16 bf16x8 __attribute__((ext_vector_type(8)));
typedef float floatx4 __attribute__((ext_vector_type(4)));
typedef unsigned short ushort8v __attribute__((ext_vector_type(8)));
typedef unsigned short ushort4v __attribute__((ext_vector_type(4)));
typedef unsigned short ushort2v __attribute__((ext_vector_type(2)));

#define DEV static __device__ __forceinline__

DEV unsigned short f2bf(float f) {
  union { float f; unsigned u; } v; v.f = f;
  unsigned r = v.u + 0x7fffu + ((v.u >> 16) & 1u);
  return (unsigned short)(r >> 16);
}
DEV float bf2f(unsigned short b) {
  union { unsigned u; float f; } v; v.u = ((unsigned)b) << 16;
  return v.f;
}

// async global->LDS, 16B per lane; lds must be wave-uniform base (lane i lands
// at base + i*16)  [guide §5, m97]
DEV void gload_lds16(const void* g, void* lds) {
  __builtin_amdgcn_global_load_lds(
      (__attribute__((address_space(1))) void*)(g),
      (__attribute__((address_space(3))) void*)(lds), 16, 0, 0);
}

// ---------------------------------------------------------------------------
// fp32 -> bf16 elementwise (x)
// ---------------------------------------------------------------------------
__global__ __launch_bounds__(256) void cvt_fp32_bf16(
    const float* __restrict__ in, unsigned short* __restrict__ out, int n4) {
  int i = blockIdx.x * 256 + threadIdx.x;
  if (i >= n4) return;
  float4 v = ((const float4*)in)[i];
  ushort4v w;
  w.x = f2bf(v.x); w.y = f2bf(v.y); w.z = f2bf(v.z); w.w = f2bf(v.w);
  *(ushort4v*)(out + (size_t)i * 4) = w;
}

// ---------------------------------------------------------------------------
// fp32 (K x N) -> bf16 (N x K) tiled transpose+convert
// ---------------------------------------------------------------------------
__global__ __launch_bounds__(256) void transpose_cvt(
    const float* __restrict__ in, unsigned short* __restrict__ out, int K, int N) {
  __shared__ float tile[32][33];
  int k0 = blockIdx.x * 32, n0 = blockIdx.y * 32;
  int tx = threadIdx.x & 31, ty = threadIdx.x >> 5;
  for (int i = 0; i < 32; i += 8)
    tile[ty + i][tx] = in[(size_t)(k0 + ty + i) * N + n0 + tx];
  __syncthreads();
  for (int i = 0; i < 32; i += 8)
    out[(size_t)(n0 + ty + i) * K + k0 + tx] = f2bf(tile[tx][ty + i]);
}

// ---------------------------------------------------------------------------
// GEMM: C[M,N] = A[M,K] * B[K,N], with B supplied transposed (Bt[N,K]).
// bf16 inputs, fp32 accumulate. 128x128 tile, BK=32, 256 thr (4 waves, 2x2).
// LDS is quad-major ([kquad][row][8]) so global_load_lds staging is
// lane-contiguous AND ds_read_b128 fragment reads are bank-clean.
// STORE_F32: 1 -> fp32 C, 0 -> bf16 C.
// ---------------------------------------------------------------------------
template <int STORE_F32>
__global__ __launch_bounds__(256, 2) void gemm_bt(
    const unsigned short* __restrict__ A, const unsigned short* __restrict__ Bt,
    void* __restrict__ Cp, int M, int N, int K) {
  __shared__ __align__(16) unsigned short a_lds[4096];  // [quad][128][8]
  __shared__ __align__(16) unsigned short b_lds[4096];
  const int tid = threadIdx.x;
  const int wave = tid >> 6, lane = tid & 63;
  const int quad = lane >> 4, l16 = lane & 15;
  const int m0 = blockIdx.x * 128, n0 = blockIdx.y * 128;
  const int wm = (wave >> 1) * 64, wn = (wave & 1) * 64;

  floatx4 acc[4][4] = {};

  for (int k0 = 0; k0 < K; k0 += 32) {
    __syncthreads();
    for (int s = 0; s < 2; ++s) {
      int t = wave * 2 + s;        // global issue id 0..7
      int g = t * 64 + lane;       // 0..511
      int q = g >> 7, r = g & 127; // kquad, row
      gload_lds16(A + (size_t)(m0 + r) * K + k0 + q * 8, a_lds + t * 512);
      gload_lds16(Bt + (size_t)(n0 + r) * K + k0 + q * 8, b_lds + t * 512);
    }
    __syncthreads();
    bf16x8 af[4], bfr[4];
    for (int i = 0; i < 4; ++i)
      af[i] = *(const bf16x8*)(a_lds + quad * 1024 + (wm + i * 16 + l16) * 8);
    for (int j = 0; j < 4; ++j)
      bfr[j] = *(const bf16x8*)(b_lds + quad * 1024 + (wn + j * 16 + l16) * 8);
    for (int i = 0; i < 4; ++i)
      for (int j = 0; j < 4; ++j)
        acc[i][j] =
            __builtin_amdgcn_mfma_f32_16x16x32_bf16(af[i], bfr[j], acc[i][j], 0, 0, 0);
  }

  for (int i = 0; i < 4; ++i)
    for (int j = 0; j < 4; ++j)
      for (int r = 0; r < 4; ++r) {
        int row = m0 + wm + i * 16 + quad * 4 + r;
        int col = n0 + wn + j * 16 + l16;
        float v = acc[i][j][r];
        if (STORE_F32)
          ((float*)Cp)[(size_t)row * N + col] = v;
        else
          ((unsigned short*)Cp)[(size_t)row * N + col] = f2bf(v);
      }
}

// ---------------------------------------------------------------------------
// RoPE Q: qkv bf16 (4096 x 6144) cols [0,4096) -> Q (b,h,s,128) bf16
// ---------------------------------------------------------------------------
__global__ __launch_bounds__(256) void rope_q(
    const unsigned short* __restrict__ qkv, const float* __restrict__ fc,
    const float* __restrict__ fs, unsigned short* __restrict__ Qd) {
  int gid = blockIdx.x * 256 + threadIdx.x;  // B*S*H*64 = 8388608
  int i = gid & 63;
  int h = (gid >> 6) & 31;
  int s = (gid >> 11) & 2047;
  int b = gid >> 22;
  int row = b * 2048 + s;
  ushort2v p = *(const ushort2v*)(qkv + (size_t)row * 6144 + h * 128 + 2 * i);
  float a = bf2f(p.x), bb = bf2f(p.y);
  float c = fc[s * 64 + i], sn = fs[s * 64 + i];
  ushort2v w;
  w.x = f2bf(a * c - bb * sn);
  w.y = f2bf(a * sn + bb * c);
  *(ushort2v*)(Qd + ((((size_t)b * 32 + h) * 2048 + s) * 128 + 2 * i)) = w;
}

// ---------------------------------------------------------------------------
// RoPE K: qkv cols [4096,5120) -> K (b,kvh,s,128) bf16
// ---------------------------------------------------------------------------
__global__ __launch_bounds__(256) void rope_k(
    const unsigned short* __restrict__ qkv, const float* __restrict__ fc,
    const float* __restrict__ fs, unsigned short* __restrict__ Kd) {
  int gid = blockIdx.x * 256 + threadIdx.x;  // B*S*KVH*64 = 2097152
  int i = gid & 63;
  int kvh = (gid >> 6) & 7;
  int s = (gid >> 9) & 2047;
  int b = gid >> 20;
  int row = b * 2048 + s;
  ushort2v p = *(const ushort2v*)(qkv + (size_t)row * 6144 + 4096 + kvh * 128 + 2 * i);
  float a = bf2f(p.x), bb = bf2f(p.y);
  float c = fc[s * 64 + i], sn = fs[s * 64 + i];
  ushort2v w;
  w.x = f2bf(a * c - bb * sn);
  w.y = f2bf(a * sn + bb * c);
  *(ushort2v*)(Kd + ((((size_t)b * 8 + kvh) * 2048 + s) * 128 + 2 * i)) = w;
}

// ---------------------------------------------------------------------------
// V transpose: qkv cols [5120,6144) (s-major) -> Vt (b,kvh,128,2048) d-major
// ---------------------------------------------------------------------------
__global__ __launch_bounds__(256) void vtrans(
    const unsigned short* __restrict__ qkv, unsigned short* __restrict__ Vt) {
  __shared__ unsigned short tile[32][33];
  int bk = blockIdx.z;                 // b*8+kvh
  int b = bk >> 3, kvh = bk & 7;
  int s0 = blockIdx.x * 32, d0 = blockIdx.y * 32;
  int tx = threadIdx.x & 31, ty = threadIdx.x >> 5;
  for (int i = 0; i < 32; i += 8)
    tile[ty + i][tx] =
        qkv[(size_t)(b * 2048 + s0 + ty + i) * 6144 + 5120 + kvh * 128 + d0 + tx];
  __syncthreads();
  for (int i = 0; i < 32; i += 8)
    Vt[((size_t)bk * 128 + d0 + ty + i) * 2048 + s0 + tx] = tile[tx][ty + i];
}

// ---------------------------------------------------------------------------
// Flash attention, causal, GQA. One block = (b, h, 64 q-rows); 4 waves each
// own 16 q-rows. 64-key iterations. Online softmax state per lane covers
// rows quad*4..quad*4+3 (replicated across the 16 lanes of a quad).
// Verified MFMA contract: a=A[m=l16][k=quad*8+j], b=Bt[n=l16][k=quad*8+j],
// D[row=quad*4+r][col=l16].
// ---------------------------------------------------------------------------
__global__ __launch_bounds__(256, 2) void attn_kernel(
    const unsigned short* __restrict__ Q,   // (b,h,s,128)
    const unsigned short* __restrict__ Kd,  // (b,kvh,s,128)
    const unsigned short* __restrict__ Vt,  // (b,kvh,128,s)
    unsigned short* __restrict__ O) {       // (b*s, 4096)
  __shared__ __align__(16) unsigned short k_lds[64][136];   // [key][d] +pad
  __shared__ __align__(16) unsigned short v_lds[128][72];   // [d][key] +pad
  __shared__ __align__(16) unsigned short p_lds[4][16][72]; // per-wave P

  const int tid = threadIdx.x;
  const int wave = tid >> 6, lane = tid & 63;
  const int quad = lane >> 4, l16 = lane & 15;
  const int q0 = blockIdx.x * 64;
  const int h = blockIdx.y;
  const int b = blockIdx.z;
  const int kvh = h >> 2;
  const float scale = 0.08838834764831845f;  // 1/sqrt(128)

  const unsigned short* qrow =
      Q + (((size_t)b * 32 + h) * 2048 + q0 + wave * 16 + l16) * 128;
  bf16x8 qf[4];
  for (int t = 0; t < 4; ++t)
    qf[t] = *(const bf16x8*)(qrow + t * 32 + quad * 8);

  float m_i[4], l_i[4];
  for (int r = 0; r < 4; ++r) { m_i[r] = -3.0e38f; l_i[r] = 0.f; }
  floatx4 o_acc[8] = {};

  const unsigned short* kbase = Kd + ((size_t)b * 8 + kvh) * 2048 * 128;
  const unsigned short* vbase = Vt + ((size_t)b * 8 + kvh) * 128 * 2048;

  for (int kb = 0; kb <= q0; kb += 64) {
    __syncthreads();  // protect LDS reuse from previous iteration's readers
    // stage K tile: 64 keys x 128 d  (1024 ushort8 chunks -> 4 steps)
    for (int s = 0; s < 4; ++s) {
      int g = s * 256 + tid;
      int key = g >> 4, dq = g & 15;
      *(ushort8v*)&k_lds[key][dq * 8] =
          *(const ushort8v*)(kbase + (size_t)(kb + key) * 128 + dq * 8);
    }
    // stage V^T tile: 128 d x 64 keys  (1024 ushort8 chunks -> 4 steps)
    for (int s = 0; s < 4; ++s) {
      int g = s * 256 + tid;
      int d = g >> 3, sq = g & 7;
      *(ushort8v*)&v_lds[d][sq * 8] =
          *(const ushort8v*)(vbase + (size_t)d * 2048 + kb + sq * 8);
    }
    __syncthreads();

    // S = scale * Q K^T  (16 q-rows x 64 keys per wave)
    float sv[4][4];
    for (int kt = 0; kt < 4; ++kt) {
      floatx4 a = {0.f, 0.f, 0.f, 0.f};
      for (int t = 0; t < 4; ++t) {
        bf16x8 kf = *(const bf16x8*)&k_lds[kt * 16 + l16][t * 32 + quad * 8];
        a = __builtin_amdgcn_mfma_f32_16x16x32_bf16(qf[t], kf, a, 0, 0, 0);
      }
      for (int r = 0; r < 4; ++r) sv[kt][r] = a[r] * scale;
    }
    if (kb == q0) {  // diagonal block: causal mask
      for (int kt = 0; kt < 4; ++kt) {
        int kcol = kb + kt * 16 + l16;
        for (int r = 0; r < 4; ++r) {
          int qg = q0 + wave * 16 + quad * 4 + r;
          if (kcol > qg) sv[kt][r] -= 1.0e9f;
        }
      }
    }
    // online softmax
    float mnew[4], alpha[4];
    for (int r = 0; r < 4; ++r) {
      float mx = fmaxf(fmaxf(sv[0][r], sv[1][r]), fmaxf(sv[2][r], sv[3][r]));
      for (int off = 1; off < 16; off <<= 1)
        mx = fmaxf(mx, __shfl_xor(mx, off));
      mnew[r] = fmaxf(m_i[r], mx);
      alpha[r] = __expf(m_i[r] - mnew[r]);
      m_i[r] = mnew[r];
    }
    for (int r = 0; r < 4; ++r) {
      float sum = 0.f;
      for (int kt = 0; kt < 4; ++kt) {
        float p = __expf(sv[kt][r] - mnew[r]);
        sv[kt][r] = p;
        sum += p;
      }
      for (int off = 1; off < 16; off <<= 1)
        sum += __shfl_xor(sum, off);
      l_i[r] = l_i[r] * alpha[r] + sum;
    }
    for (int nb = 0; nb < 8; ++nb)
      for (int r = 0; r < 4; ++r) o_acc[nb][r] *= alpha[r];
    // P: C-layout -> LDS -> A-layout (m120 pattern)
    for (int kt = 0; kt < 4; ++kt)
      for (int r = 0; r < 4; ++r)
        p_lds[wave][quad * 4 + r][kt * 16 + l16] = f2bf(sv[kt][r]);
    __syncthreads();
    // O += P V
    for (int tk = 0; tk < 2; ++tk) {
      bf16x8 pa = *(const bf16x8*)&p_lds[wave][l16][tk * 32 + quad * 8];
      for (int nb = 0; nb < 8; ++nb) {
        bf16x8 vb = *(const bf16x8*)&v_lds[nb * 16 + l16][tk * 32 + quad * 8];
        o_acc[nb] = __builtin_amdgcn_mfma_f32_16x16x32_bf16(pa, vb, o_acc[nb], 0, 0, 0);
      }
    }
  }

  for (int nb = 0; nb < 8; ++nb)
    for (int r = 0; r < 4; ++r) {
      int row = b * 2048 + q0 + wave * 16 + quad * 4 + r;
      int col = h * 128 + nb * 16 + l16;
      O[(size_t)row * 4096 + col] = f2bf(o_acc[nb][r] / l_i[r]);
    }
}

// ---------------------------------------------------------------------------
// Launcher.  Workspace layout (144 MB, with aliasing):
//   [0,   32M)  xb  (x in bf16)           -> later reused as Q (b,h,s,d)
//   [32M, 80M)  wT  (qkv weights, N x K)  -> later reused as w_oT
//   [80M, 128M) qkv (4096 x 6144 bf16)    -> later reused as O (attn out)
//   [128M,136M) Kd  (b,kvh,s,d)
//   [136M,144M) Vt  (b,kvh,d,s)
// ---------------------------------------------------------------------------
extern "C" void kernel_launch(void* const* d_in, const int* in_sizes, int n_in,
                              void* d_out, int out_size, void* d_ws, size_t ws_size,
                              hipStream_t stream) {
  const float* x   = (const float*)d_in[0];
  const float* w_q = (const float*)d_in[1];
  const float* w_k = (const float*)d_in[2];
  const float* w_v = (const float*)d_in[3];
  const float* w_o = (const float*)d_in[4];
  const float* fc  = (const float*)d_in[5];
  const float* fs  = (const float*)d_in[6];
  (void)in_sizes; (void)n_in; (void)out_size; (void)ws_size;

  char* ws = (char*)d_ws;
  unsigned short* xb  = (unsigned short*)(ws);
  unsigned short* wT  = (unsigned short*)(ws + 33554432ull);
  unsigned short* qkv = (unsigned short*)(ws + 83886080ull);
  unsigned short* Kd  = (unsigned short*)(ws + 134217728ull);
  unsigned short* Vt  = (unsigned short*)(ws + 142606336ull);
  unsigned short* Qd  = xb;   // alias: xb dead after gemm1
  unsigned short* woT = wT;   // alias: wT dead after gemm1
  unsigned short* Ob  = qkv;  // alias: qkv dead after rope/vtrans

  cvt_fp32_bf16<<<16384, 256, 0, stream>>>(x, xb, 4194304);
  transpose_cvt<<<dim3(128, 128), 256, 0, stream>>>(w_q, wT, 4096, 4096);
  transpose_cvt<<<dim3(128, 32), 256, 0, stream>>>(w_k, wT + (size_t)4096 * 4096, 4096, 1024);
  transpose_cvt<<<dim3(128, 32), 256, 0, stream>>>(w_v, wT + (size_t)5120 * 4096, 4096, 1024);
  gemm_bt<0><<<dim3(32, 48), 256, 0, stream>>>(xb, wT, qkv, 4096, 6144, 4096);
  transpose_cvt<<<dim3(128, 128), 256, 0, stream>>>(w_o, woT, 4096, 4096);
  rope_q<<<32768, 256, 0, stream>>>(qkv, fc, fs, Qd);
  rope_k<<<8192, 256, 0, stream>>>(qkv, fc, fs, Kd);
  vtrans<<<dim3(64, 4, 16), 256, 0, stream>>>(qkv, Vt);
  attn_kernel<<<dim3(32, 32, 2), 256, 0, stream>>>(Qd, Kd, Vt, Ob);
  gemm_bt<1><<<dim3(32, 32), 256, 0, stream>>>(Ob, woT, d_out, 4096, 4096, 4096);
}

// Round 3
// 968.824 us; speedup vs baseline: 1.2701x; 1.2701x over previous
//
#include <hip/hip_runtime.h>
#include <stdint.h>
#include <stddef.h>

// ---------------------------------------------------------------------------
// GQA forward: y = Attn(RoPE(x@Wq), RoPE(x@Wk), x@Wv) @ Wo
// B=2 S=2048 D=4096 H=32 KVH=8 Dh=128, causal, fp32 in/out, bf16 MFMA compute.
// ---------------------------------------------------------------------------

typedef __bf16 bf16x8 __attribute__((ext_vector_type(8)));
typedef float floatx4 __attribute__((ext_vector_type(4)));
typedef unsigned short ushort8v __attribute__((ext_vector_type(8)));
typedef unsigned short ushort4v __attribute__((ext_vector_type(4)));
typedef unsigned short ushort2v __attribute__((ext_vector_type(2)));

#define DEV static __device__ __forceinline__

DEV unsigned short f2bf(float f) {
  union { float f; unsigned u; } v; v.f = f;
  unsigned r = v.u + 0x7fffu + ((v.u >> 16) & 1u);
  return (unsigned short)(r >> 16);
}
DEV float bf2f(unsigned short b) {
  union { unsigned u; float f; } v; v.u = ((unsigned)b) << 16;
  return v.f;
}

// async global->LDS, 16B per lane; lds dest is wave-uniform base + lane*16
DEV void gload_lds16(const void* g, void* lds) {
  __builtin_amdgcn_global_load_lds(
      (__attribute__((address_space(1))) void*)(g),
      (__attribute__((address_space(3))) void*)(lds), 16, 0, 0);
}

// ---------------------------------------------------------------------------
// fp32 -> bf16 elementwise (x)
// ---------------------------------------------------------------------------
__global__ __launch_bounds__(256) void cvt_fp32_bf16(
    const float* __restrict__ in, unsigned short* __restrict__ out, int n4) {
  int i = blockIdx.x * 256 + threadIdx.x;
  if (i >= n4) return;
  float4 v = ((const float4*)in)[i];
  ushort4v w;
  w.x = f2bf(v.x); w.y = f2bf(v.y); w.z = f2bf(v.z); w.w = f2bf(v.w);
  *(ushort4v*)(out + (size_t)i * 4) = w;
}

// ---------------------------------------------------------------------------
// fp32 (K x N) -> bf16 (N x K) tiled transpose+convert
// ---------------------------------------------------------------------------
__global__ __launch_bounds__(256) void transpose_cvt(
    const float* __restrict__ in, unsigned short* __restrict__ out, int K, int N) {
  __shared__ float tile[32][33];
  int k0 = blockIdx.x * 32, n0 = blockIdx.y * 32;
  int tx = threadIdx.x & 31, ty = threadIdx.x >> 5;
  for (int i = 0; i < 32; i += 8)
    tile[ty + i][tx] = in[(size_t)(k0 + ty + i) * N + n0 + tx];
  __syncthreads();
  for (int i = 0; i < 32; i += 8)
    out[(size_t)(n0 + ty + i) * K + k0 + tx] = f2bf(tile[tx][ty + i]);
}

// ---------------------------------------------------------------------------
// GEMM: C[M,N] = A[M,K] * B[K,N], with B supplied transposed (Bt[N,K]).
// bf16 inputs, fp32 accumulate. 128x128 tile, BK=32, 256 thr (4 waves, 2x2).
// LDS layout: row-major [128 rows][4 chunks of 8 k-elems], with the chunk
// position XOR-swizzled by (row&3):
//   position p of row r holds global k-chunk  q = p ^ (r&3).
// Write (global_load_lds, lane c of issue t): row = t*16 + (c>>2),
//   global chunk = (c&3) ^ ((c>>2)&3)  -> 4 lanes/row = contiguous 64 B
//   global segment (coalesced), LDS dest = base + c*16 (HW constraint).
// Read (fragment row rm, k-chunk quad): position = quad ^ (rm&3); bank
//   starts cycle {0,20,8,28} -> 8 words/bank/instr = the b128 floor.
// STORE_F32: 1 -> fp32 C, 0 -> bf16 C.
// ---------------------------------------------------------------------------
template <int STORE_F32>
__global__ __launch_bounds__(256, 2) void gemm_bt(
    const unsigned short* __restrict__ A, const unsigned short* __restrict__ Bt,
    void* __restrict__ Cp, int M, int N, int K) {
  __shared__ __align__(16) unsigned short a_lds[4096];  // [128][32], swizzled
  __shared__ __align__(16) unsigned short b_lds[4096];
  const int tid = threadIdx.x;
  const int wave = tid >> 6, lane = tid & 63;
  const int quad = lane >> 4, l16 = lane & 15;
  const int m0 = blockIdx.x * 128, n0 = blockIdx.y * 128;
  const int wm = (wave >> 1) * 64, wn = (wave & 1) * 64;

  // staging address components (per-thread constants)
  const int srow = (lane >> 2);                       // 0..15 within issue
  const int skq = (lane & 3) ^ ((lane >> 2) & 3);     // swizzled k-chunk

  floatx4 acc[4][4] = {};

  for (int k0 = 0; k0 < K; k0 += 32) {
    __syncthreads();
    for (int s = 0; s < 2; ++s) {
      int t = wave * 2 + s;            // issue id 0..7 -> rows t*16..t*16+15
      int row = t * 16 + srow;
      gload_lds16(A + (size_t)(m0 + row) * K + k0 + skq * 8, a_lds + t * 512);
      gload_lds16(Bt + (size_t)(n0 + row) * K + k0 + skq * 8, b_lds + t * 512);
    }
    __syncthreads();
    bf16x8 af[4], bfr[4];
    const int pos = (quad ^ (l16 & 3)) * 8;
    for (int i = 0; i < 4; ++i)
      af[i] = *(const bf16x8*)(a_lds + (wm + i * 16 + l16) * 32 + pos);
    for (int j = 0; j < 4; ++j)
      bfr[j] = *(const bf16x8*)(b_lds + (wn + j * 16 + l16) * 32 + pos);
    for (int i = 0; i < 4; ++i)
      for (int j = 0; j < 4; ++j)
        acc[i][j] =
            __builtin_amdgcn_mfma_f32_16x16x32_bf16(af[i], bfr[j], acc[i][j], 0, 0, 0);
  }

  for (int i = 0; i < 4; ++i)
    for (int j = 0; j < 4; ++j)
      for (int r = 0; r < 4; ++r) {
        int row = m0 + wm + i * 16 + quad * 4 + r;
        int col = n0 + wn + j * 16 + l16;
        float v = acc[i][j][r];
        if (STORE_F32)
          ((float*)Cp)[(size_t)row * N + col] = v;
        else
          ((unsigned short*)Cp)[(size_t)row * N + col] = f2bf(v);
      }
}

// ---------------------------------------------------------------------------
// RoPE Q: qkv bf16 (4096 x 6144) cols [0,4096) -> Q (b,h,s,128) bf16
// ---------------------------------------------------------------------------
__global__ __launch_bounds__(256) void rope_q(
    const unsigned short* __restrict__ qkv, const float* __restrict__ fc,
    const float* __restrict__ fs, unsigned short* __restrict__ Qd) {
  int gid = blockIdx.x * 256 + threadIdx.x;  // B*S*H*64 = 8388608
  int i = gid & 63;
  int h = (gid >> 6) & 31;
  int s = (gid >> 11) & 2047;
  int b = gid >> 22;
  int row = b * 2048 + s;
  ushort2v p = *(const ushort2v*)(qkv + (size_t)row * 6144 + h * 128 + 2 * i);
  float a = bf2f(p.x), bb = bf2f(p.y);
  float c = fc[s * 64 + i], sn = fs[s * 64 + i];
  ushort2v w;
  w.x = f2bf(a * c - bb * sn);
  w.y = f2bf(a * sn + bb * c);
  *(ushort2v*)(Qd + ((((size_t)b * 32 + h) * 2048 + s) * 128 + 2 * i)) = w;
}

// ---------------------------------------------------------------------------
// RoPE K: qkv cols [4096,5120) -> K (b,kvh,s,128) bf16
// ---------------------------------------------------------------------------
__global__ __launch_bounds__(256) void rope_k(
    const unsigned short* __restrict__ qkv, const float* __restrict__ fc,
    const float* __restrict__ fs, unsigned short* __restrict__ Kd) {
  int gid = blockIdx.x * 256 + threadIdx.x;  // B*S*KVH*64 = 2097152
  int i = gid & 63;
  int kvh = (gid >> 6) & 7;
  int s = (gid >> 9) & 2047;
  int b = gid >> 20;
  int row = b * 2048 + s;
  ushort2v p = *(const ushort2v*)(qkv + (size_t)row * 6144 + 4096 + kvh * 128 + 2 * i);
  float a = bf2f(p.x), bb = bf2f(p.y);
  float c = fc[s * 64 + i], sn = fs[s * 64 + i];
  ushort2v w;
  w.x = f2bf(a * c - bb * sn);
  w.y = f2bf(a * sn + bb * c);
  *(ushort2v*)(Kd + ((((size_t)b * 8 + kvh) * 2048 + s) * 128 + 2 * i)) = w;
}

// ---------------------------------------------------------------------------
// V transpose: qkv cols [5120,6144) (s-major) -> Vt (b,kvh,128,2048) d-major
// ---------------------------------------------------------------------------
__global__ __launch_bounds__(256) void vtrans(
    const unsigned short* __restrict__ qkv, unsigned short* __restrict__ Vt) {
  __shared__ unsigned short tile[32][33];
  int bk = blockIdx.z;                 // b*8+kvh
  int b = bk >> 3, kvh = bk & 7;
  int s0 = blockIdx.x * 32, d0 = blockIdx.y * 32;
  int tx = threadIdx.x & 31, ty = threadIdx.x >> 5;
  for (int i = 0; i < 32; i += 8)
    tile[ty + i][tx] =
        qkv[(size_t)(b * 2048 + s0 + ty + i) * 6144 + 5120 + kvh * 128 + d0 + tx];
  __syncthreads();
  for (int i = 0; i < 32; i += 8)
    Vt[((size_t)bk * 128 + d0 + ty + i) * 2048 + s0 + tx] = tile[tx][ty + i];
}

// ---------------------------------------------------------------------------
// Flash attention, causal, GQA. One block = (b, h, 64 q-rows); 4 waves each
// own 16 q-rows. 64-key iterations. Online softmax state per lane covers
// rows quad*4..quad*4+3 (replicated across the 16 lanes of a quad).
// Verified MFMA contract: a=A[m=l16][k=quad*8+j], b=Bt[n=l16][k=quad*8+j],
// D[row=quad*4+r][col=l16].
// ---------------------------------------------------------------------------
__global__ __launch_bounds__(256, 2) void attn_kernel(
    const unsigned short* __restrict__ Q,   // (b,h,s,128)
    const unsigned short* __restrict__ Kd,  // (b,kvh,s,128)
    const unsigned short* __restrict__ Vt,  // (b,kvh,128,s)
    unsigned short* __restrict__ O) {       // (b*s, 4096)
  __shared__ __align__(16) unsigned short k_lds[64][136];   // [key][d] +pad
  __shared__ __align__(16) unsigned short v_lds[128][72];   // [d][key] +pad
  __shared__ __align__(16) unsigned short p_lds[4][16][72]; // per-wave P

  const int tid = threadIdx.x;
  const int wave = tid >> 6, lane = tid & 63;
  const int quad = lane >> 4, l16 = lane & 15;
  const int q0 = blockIdx.x * 64;
  const int h = blockIdx.y;
  const int b = blockIdx.z;
  const int kvh = h >> 2;
  const float scale = 0.08838834764831845f;  // 1/sqrt(128)

  const unsigned short* qrow =
      Q + (((size_t)b * 32 + h) * 2048 + q0 + wave * 16 + l16) * 128;
  bf16x8 qf[4];
  for (int t = 0; t < 4; ++t)
    qf[t] = *(const bf16x8*)(qrow + t * 32 + quad * 8);

  float m_i[4], l_i[4];
  for (int r = 0; r < 4; ++r) { m_i[r] = -3.0e38f; l_i[r] = 0.f; }
  floatx4 o_acc[8] = {};

  const unsigned short* kbase = Kd + ((size_t)b * 8 + kvh) * 2048 * 128;
  const unsigned short* vbase = Vt + ((size_t)b * 8 + kvh) * 128 * 2048;

  for (int kb = 0; kb <= q0; kb += 64) {
    __syncthreads();  // protect LDS reuse from previous iteration's readers
    // stage K tile: 64 keys x 128 d  (1024 ushort8 chunks -> 4 steps)
    for (int s = 0; s < 4; ++s) {
      int g = s * 256 + tid;
      int key = g >> 4, dq = g & 15;
      *(ushort8v*)&k_lds[key][dq * 8] =
          *(const ushort8v*)(kbase + (size_t)(kb + key) * 128 + dq * 8);
    }
    // stage V^T tile: 128 d x 64 keys  (1024 ushort8 chunks -> 4 steps)
    for (int s = 0; s < 4; ++s) {
      int g = s * 256 + tid;
      int d = g >> 3, sq = g & 7;
      *(ushort8v*)&v_lds[d][sq * 8] =
          *(const ushort8v*)(vbase + (size_t)d * 2048 + kb + sq * 8);
    }
    __syncthreads();

    // S = scale * Q K^T  (16 q-rows x 64 keys per wave)
    float sv[4][4];
    for (int kt = 0; kt < 4; ++kt) {
      floatx4 a = {0.f, 0.f, 0.f, 0.f};
      for (int t = 0; t < 4; ++t) {
        bf16x8 kf = *(const bf16x8*)&k_lds[kt * 16 + l16][t * 32 + quad * 8];
        a = __builtin_amdgcn_mfma_f32_16x16x32_bf16(qf[t], kf, a, 0, 0, 0);
      }
      for (int r = 0; r < 4; ++r) sv[kt][r] = a[r] * scale;
    }
    if (kb == q0) {  // diagonal block: causal mask
      for (int kt = 0; kt < 4; ++kt) {
        int kcol = kb + kt * 16 + l16;
        for (int r = 0; r < 4; ++r) {
          int qg = q0 + wave * 16 + quad * 4 + r;
          if (kcol > qg) sv[kt][r] -= 1.0e9f;
        }
      }
    }
    // online softmax
    float mnew[4], alpha[4];
    for (int r = 0; r < 4; ++r) {
      float mx = fmaxf(fmaxf(sv[0][r], sv[1][r]), fmaxf(sv[2][r], sv[3][r]));
      for (int off = 1; off < 16; off <<= 1)
        mx = fmaxf(mx, __shfl_xor(mx, off));
      mnew[r] = fmaxf(m_i[r], mx);
      alpha[r] = __expf(m_i[r] - mnew[r]);
      m_i[r] = mnew[r];
    }
    for (int r = 0; r < 4; ++r) {
      float sum = 0.f;
      for (int kt = 0; kt < 4; ++kt) {
        float p = __expf(sv[kt][r] - mnew[r]);
        sv[kt][r] = p;
        sum += p;
      }
      for (int off = 1; off < 16; off <<= 1)
        sum += __shfl_xor(sum, off);
      l_i[r] = l_i[r] * alpha[r] + sum;
    }
    for (int nb = 0; nb < 8; ++nb)
      for (int r = 0; r < 4; ++r) o_acc[nb][r] *= alpha[r];
    // P: C-layout -> LDS -> A-layout (m120 pattern)
    for (int kt = 0; kt < 4; ++kt)
      for (int r = 0; r < 4; ++r)
        p_lds[wave][quad * 4 + r][kt * 16 + l16] = f2bf(sv[kt][r]);
    __syncthreads();
    // O += P V
    for (int tk = 0; tk < 2; ++tk) {
      bf16x8 pa = *(const bf16x8*)&p_lds[wave][l16][tk * 32 + quad * 8];
      for (int nb = 0; nb < 8; ++nb) {
        bf16x8 vb = *(const bf16x8*)&v_lds[nb * 16 + l16][tk * 32 + quad * 8];
        o_acc[nb] = __builtin_amdgcn_mfma_f32_16x16x32_bf16(pa, vb, o_acc[nb], 0, 0, 0);
      }
    }
  }

  for (int nb = 0; nb < 8; ++nb)
    for (int r = 0; r < 4; ++r) {
      int row = b * 2048 + q0 + wave * 16 + quad * 4 + r;
      int col = h * 128 + nb * 16 + l16;
      O[(size_t)row * 4096 + col] = f2bf(o_acc[nb][r] / l_i[r]);
    }
}

// ---------------------------------------------------------------------------
// Launcher.  Workspace layout (144 MB, with aliasing):
//   [0,   32M)  xb  (x in bf16)           -> later reused as Q (b,h,s,d)
//   [32M, 80M)  wT  (qkv weights, N x K)  -> later reused as w_oT
//   [80M, 128M) qkv (4096 x 6144 bf16)    -> later reused as O (attn out)
//   [128M,136M) Kd  (b,kvh,s,d)
//   [136M,144M) Vt  (b,kvh,d,s)
// ---------------------------------------------------------------------------
extern "C" void kernel_launch(void* const* d_in, const int* in_sizes, int n_in,
                              void* d_out, int out_size, void* d_ws, size_t ws_size,
                              hipStream_t stream) {
  const float* x   = (const float*)d_in[0];
  const float* w_q = (const float*)d_in[1];
  const float* w_k = (const float*)d_in[2];
  const float* w_v = (const float*)d_in[3];
  const float* w_o = (const float*)d_in[4];
  const float* fc  = (const float*)d_in[5];
  const float* fs  = (const float*)d_in[6];
  (void)in_sizes; (void)n_in; (void)out_size; (void)ws_size;

  char* ws = (char*)d_ws;
  unsigned short* xb  = (unsigned short*)(ws);
  unsigned short* wT  = (unsigned short*)(ws + 33554432ull);
  unsigned short* qkv = (unsigned short*)(ws + 83886080ull);
  unsigned short* Kd  = (unsigned short*)(ws + 134217728ull);
  unsigned short* Vt  = (unsigned short*)(ws + 142606336ull);
  unsigned short* Qd  = xb;   // alias: xb dead after gemm1
  unsigned short* woT = wT;   // alias: wT dead after gemm1
  unsigned short* Ob  = qkv;  // alias: qkv dead after rope/vtrans

  cvt_fp32_bf16<<<16384, 256, 0, stream>>>(x, xb, 4194304);
  transpose_cvt<<<dim3(128, 128), 256, 0, stream>>>(w_q, wT, 4096, 4096);
  transpose_cvt<<<dim3(128, 32), 256, 0, stream>>>(w_k, wT + (size_t)4096 * 4096, 4096, 1024);
  transpose_cvt<<<dim3(128, 32), 256, 0, stream>>>(w_v, wT + (size_t)5120 * 4096, 4096, 1024);
  gemm_bt<0><<<dim3(32, 48), 256, 0, stream>>>(xb, wT, qkv, 4096, 6144, 4096);
  transpose_cvt<<<dim3(128, 128), 256, 0, stream>>>(w_o, woT, 4096, 4096);
  rope_q<<<32768, 256, 0, stream>>>(qkv, fc, fs, Qd);
  rope_k<<<8192, 256, 0, stream>>>(qkv, fc, fs, Kd);
  vtrans<<<dim3(64, 4, 16), 256, 0, stream>>>(qkv, Vt);
  attn_kernel<<<dim3(32, 32, 2), 256, 0, stream>>>(Qd, Kd, Vt, Ob);
  gemm_bt<1><<<dim3(32, 32), 256, 0, stream>>>(Ob, woT, d_out, 4096, 4096, 4096);
}